// Round 13
// baseline (175.393 us; speedup 1.0000x reference)
//
#include <hip/hip_runtime.h>
#include <hip/hip_bf16.h>

// GraphAttentionLayer fused kernels for MI355X (gfx950).
// N=8192, IN=512, OUT=64. adj read (256MB, ~half LLC-resident) => 20-37us floor.
// r13: occupancy fixes. r12's wh ran 1 wave/SIMD (latency-exposed serial FMA
// chains); attn ran 1 block/CU. Now: wh 1024 blocks (2 rows/wave, 16 waves/CU);
// attn 512 blocks x 16 rows (52KB LDS -> 2 blocks/CU, 16 waves/CU), phase 1
// packs 2 rows/wave with 4 int4 loads in flight, phase 2 single row-group.

#define LOG2E 1.4426950408889634f

typedef __attribute__((ext_vector_type(8))) short  short8v;
typedef __attribute__((ext_vector_type(4))) float  f32x4;

__device__ __forceinline__ unsigned short f2bf(float f) {
    union { float f; unsigned int u; } x; x.f = f;
    unsigned int r = x.u + 0x7FFFu + ((x.u >> 16) & 1u);   // RNE
    return (unsigned short)(r >> 16);
}

// ---------------- Kernel 1: wh (r6 form: 1024 blocks, 2 rows/wave) ----------
__global__ __launch_bounds__(256) void wh_kernel(
        const float* __restrict__ h, const float* __restrict__ W,
        const float* __restrict__ a,
        unsigned short* __restrict__ WhbT,
        float* __restrict__ Wh1L, float* __restrict__ W2L) {
    const int wave = threadIdx.x >> 6;
    const int lane = threadIdx.x & 63;
    const int row0 = (blockIdx.x * 4 + wave) * 2;

    float acc0 = 0.f, acc1 = 0.f;
    const float* h0 = h + (size_t)row0 * 512;
    const float* h1 = h0 + 512;
    for (int i = 0; i < 512; i += 4) {
        float w0 = W[(i + 0) * 64 + lane];
        float w1 = W[(i + 1) * 64 + lane];
        float w2 = W[(i + 2) * 64 + lane];
        float w3 = W[(i + 3) * 64 + lane];
        float4 hv0 = *reinterpret_cast<const float4*>(h0 + i);
        float4 hv1 = *reinterpret_cast<const float4*>(h1 + i);
        acc0 = fmaf(hv0.x, w0, fmaf(hv0.y, w1, fmaf(hv0.z, w2, fmaf(hv0.w, w3, acc0))));
        acc1 = fmaf(hv1.x, w0, fmaf(hv1.y, w1, fmaf(hv1.z, w2, fmaf(hv1.w, w3, acc1))));
    }

    ushort2 bt;
    bt.x = f2bf(acc0);
    bt.y = f2bf(acc1);
    *reinterpret_cast<ushort2*>(WhbT + (size_t)lane * 8192 + row0) = bt;

    const float a1 = a[lane] * LOG2E, a2 = a[lane + 64] * LOG2E;
    float t10 = acc0 * a1, t20 = acc0 * a2;
    float t11 = acc1 * a1, t21 = acc1 * a2;
#pragma unroll
    for (int off = 32; off; off >>= 1) {
        t10 += __shfl_xor(t10, off);
        t20 += __shfl_xor(t20, off);
        t11 += __shfl_xor(t11, off);
        t21 += __shfl_xor(t21, off);
    }
    if (lane == 0) {
        Wh1L[row0] = t10; Wh1L[row0 + 1] = t11;
        W2L[row0]  = t20; W2L[row0 + 1]  = t21;
    }
}

// ---------------- Kernel 2: fused pack + mask + softmax + PV ----------------
// grid 512 x 512 (8 waves). Block: 16 rows x 8192 cols. 2 blocks/CU.
__global__ __launch_bounds__(512) void attn_kernel(
        const int* __restrict__ adj,
        const unsigned short* __restrict__ WhbT,
        const float* __restrict__ Wh1L, const float* __restrict__ W2L,
        float* __restrict__ out) {
    __shared__ unsigned int bm_lds[16][260];   // 16.6KB
    __shared__ float sm_acc[8][64][17];        // 34.8KB, padded
    __shared__ float sm_l[8][16];              // 0.5KB

    const int tid  = threadIdx.x;
    const int w    = tid >> 6;
    const int lane = tid & 63;
    const int fr   = lane & 15;      // MFMA row (A) / col (B,D)
    const int cg   = lane >> 4;      // k-group
    const int i0   = blockIdx.x * 16;

    // ---- phase 1: stream 2 adj rows/wave -> bitmask in LDS ----
    {
        const int rA = w * 2, rB = w * 2 + 1;
        const int* apA = adj + (size_t)(i0 + rA) * 8192 + lane * 4;
        const int* apB = adj + (size_t)(i0 + rB) * 8192 + lane * 4;
        for (int it = 0; it < 32; it += 2) {
            int4 v0 = *reinterpret_cast<const int4*>(apA + it * 256);
            int4 v1 = *reinterpret_cast<const int4*>(apA + it * 256 + 256);
            int4 v2 = *reinterpret_cast<const int4*>(apB + it * 256);
            int4 v3 = *reinterpret_cast<const int4*>(apB + it * 256 + 256);
#pragma unroll
            for (int k = 0; k < 4; ++k) {
                const int4 v  = k == 0 ? v0 : k == 1 ? v1 : k == 2 ? v2 : v3;
                const int  rr = (k < 2) ? rA : rB;
                const int  ii = it + (k & 1);
                unsigned int n = (unsigned int)(v.x > 0)
                               | ((unsigned int)(v.y > 0) << 1)
                               | ((unsigned int)(v.z > 0) << 2)
                               | ((unsigned int)(v.w > 0) << 3);
                n |= ((unsigned int)__shfl_xor((int)n, 1)) << 4;
                n |= ((unsigned int)__shfl_xor((int)n, 2)) << 8;
                n |= ((unsigned int)__shfl_xor((int)n, 4)) << 16;
                if ((lane & 7) == 0) bm_lds[rr][ii * 8 + (lane >> 3)] = n;
            }
        }
    }
    __syncthreads();

    // ---- phase 2: masked softmax numerators + PV ----
    const float wh1 = Wh1L[i0 + fr];

    f32x4 acc[4];
#pragma unroll
    for (int f = 0; f < 4; ++f) acc[f] = (f32x4){0.f, 0.f, 0.f, 0.f};
    f32x4 accl = (f32x4){0.f, 0.f, 0.f, 0.f};

    short8v ones;
#pragma unroll
    for (int b = 0; b < 8; ++b) ones[b] = (short)0x3F80;   // bf16 1.0

    const float*          w2p = W2L + w * 32 + cg * 8;
    const unsigned short* bfp = WhbT + (size_t)fr * 8192 + w * 32 + cg * 8;
    const int sh = cg * 8;

    for (int it = 0; it < 32; ++it) {
        const int cbase = it * 256;
        float4 W0 = *reinterpret_cast<const float4*>(w2p + cbase);
        float4 W1 = *reinterpret_cast<const float4*>(w2p + cbase + 4);
        short8v bf[4];
#pragma unroll
        for (int f = 0; f < 4; ++f)
            bf[f] = *reinterpret_cast<const short8v*>(bfp + (size_t)f * 16 * 8192 + cbase);

        const unsigned int wd = bm_lds[fr][it * 8 + w];

        float p[8]; float t;
        t = wh1 + W0.x; t = fmaxf(t, 0.2f * t); p[0] = ((wd >> (sh + 0)) & 1u) ? __builtin_exp2f(t) : 0.f;
        t = wh1 + W0.y; t = fmaxf(t, 0.2f * t); p[1] = ((wd >> (sh + 1)) & 1u) ? __builtin_exp2f(t) : 0.f;
        t = wh1 + W0.z; t = fmaxf(t, 0.2f * t); p[2] = ((wd >> (sh + 2)) & 1u) ? __builtin_exp2f(t) : 0.f;
        t = wh1 + W0.w; t = fmaxf(t, 0.2f * t); p[3] = ((wd >> (sh + 3)) & 1u) ? __builtin_exp2f(t) : 0.f;
        t = wh1 + W1.x; t = fmaxf(t, 0.2f * t); p[4] = ((wd >> (sh + 4)) & 1u) ? __builtin_exp2f(t) : 0.f;
        t = wh1 + W1.y; t = fmaxf(t, 0.2f * t); p[5] = ((wd >> (sh + 5)) & 1u) ? __builtin_exp2f(t) : 0.f;
        t = wh1 + W1.z; t = fmaxf(t, 0.2f * t); p[6] = ((wd >> (sh + 6)) & 1u) ? __builtin_exp2f(t) : 0.f;
        t = wh1 + W1.w; t = fmaxf(t, 0.2f * t); p[7] = ((wd >> (sh + 7)) & 1u) ? __builtin_exp2f(t) : 0.f;

        union { short8v s8; __hip_bfloat162 h2[4]; } u;
        u.h2[0] = __float22bfloat162_rn(float2{p[0], p[1]});
        u.h2[1] = __float22bfloat162_rn(float2{p[2], p[3]});
        u.h2[2] = __float22bfloat162_rn(float2{p[4], p[5]});
        u.h2[3] = __float22bfloat162_rn(float2{p[6], p[7]});

#pragma unroll
        for (int f = 0; f < 4; ++f)
            acc[f] = __builtin_amdgcn_mfma_f32_16x16x32_bf16(u.s8, bf[f], acc[f], 0, 0, 0);
        accl = __builtin_amdgcn_mfma_f32_16x16x32_bf16(u.s8, ones, accl, 0, 0, 0);
    }

    // ---- epilogue: cross-wave sums, normalize, ELU ----
    __syncthreads();
#pragma unroll
    for (int f = 0; f < 4; ++f)
#pragma unroll
        for (int reg = 0; reg < 4; ++reg)
            sm_acc[w][lane][f * 4 + reg] = acc[f][reg];
    if (fr == 0) {
#pragma unroll
        for (int reg = 0; reg < 4; ++reg) sm_l[w][4 * cg + reg] = accl[reg];
    }
    __syncthreads();

#pragma unroll
    for (int ss = 0; ss < 2; ++ss) {
        const int s = 2 * w + ss;
        const int f = s >> 2, reg = s & 3;
        float sum = 0.f;
#pragma unroll
        for (int ww = 0; ww < 8; ++ww) sum += sm_acc[ww][lane][s];
        const int R = 4 * cg + reg;
        float lrow = 0.f;
#pragma unroll
        for (int ww = 0; ww < 8; ++ww) lrow += sm_l[ww][R];
        float y = sum / lrow;
        y = y > 0.f ? y : expm1f(y);          // ELU, alpha=1
        out[(size_t)(i0 + R) * 64 + 16 * f + fr] = y;
    }
}

extern "C" void kernel_launch(void* const* d_in, const int* in_sizes, int n_in,
                              void* d_out, int out_size, void* d_ws, size_t ws_size,
                              hipStream_t stream) {
    const float* h   = (const float*)d_in[0];
    const int*   adj = (const int*)d_in[1];
    const float* W   = (const float*)d_in[2];
    const float* a   = (const float*)d_in[3];

    unsigned short* WhbT = (unsigned short*)d_ws;                    // 1 MB
    float*          Wh1L = (float*)((char*)d_ws + (1 << 20));        // 32 KB
    float*          W2L  = Wh1L + 8192;                              // 32 KB

    wh_kernel<<<1024, 256, 0, stream>>>(h, W, a, WhbT, Wh1L, W2L);
    attn_kernel<<<512, 512, 0, stream>>>(adj, WhbT, Wh1L, W2L, (float*)d_out);
}

// Round 15
// 172.995 us; speedup vs baseline: 1.0139x; 1.0139x over previous
//
#include <hip/hip_runtime.h>
#include <hip/hip_bf16.h>

// GraphAttentionLayer fused kernels for MI355X (gfx950).
// N=8192, IN=512, OUT=64.
// r13 diagnosis: attn 165us at 10% HBM / 21% VALU / LLC-warm-invariant.
// Model: 512MB of WhbT re-reads (1MB x 512 blocks) should be L2 hits (WhbT
// fits in every XCD's 4MB L2) but the 256MB adj stream THRASHES L2, forcing
// V-reads to the ~4TB/s LLC path. r15 fix (r14 had a compile error: the
// builtin needs a clang ext_vector, not HIP's int4 struct): adj loaded with
// __builtin_nontemporal_load (nt -> evict-first, no L2 pollution).
// Geometry identical to r13: wh 1024 blocks (2 rows/wave); attn 512 blocks
// x 512 thr (16 rows x 8192 cols), phase-1 pack -> bm_lds, phase-2 MFMA.

#define LOG2E 1.4426950408889634f

typedef __attribute__((ext_vector_type(8))) short  short8v;
typedef __attribute__((ext_vector_type(4))) float  f32x4;
typedef __attribute__((ext_vector_type(4))) int    int4v;

__device__ __forceinline__ unsigned short f2bf(float f) {
    union { float f; unsigned int u; } x; x.f = f;
    unsigned int r = x.u + 0x7FFFu + ((x.u >> 16) & 1u);   // RNE
    return (unsigned short)(r >> 16);
}

// ---------------- Kernel 1: wh (1024 blocks, 2 rows/wave) ----------
__global__ __launch_bounds__(256) void wh_kernel(
        const float* __restrict__ h, const float* __restrict__ W,
        const float* __restrict__ a,
        unsigned short* __restrict__ WhbT,
        float* __restrict__ Wh1L, float* __restrict__ W2L) {
    const int wave = threadIdx.x >> 6;
    const int lane = threadIdx.x & 63;
    const int row0 = (blockIdx.x * 4 + wave) * 2;

    float acc0 = 0.f, acc1 = 0.f;
    const float* h0 = h + (size_t)row0 * 512;
    const float* h1 = h0 + 512;
    for (int i = 0; i < 512; i += 4) {
        float w0 = W[(i + 0) * 64 + lane];
        float w1 = W[(i + 1) * 64 + lane];
        float w2 = W[(i + 2) * 64 + lane];
        float w3 = W[(i + 3) * 64 + lane];
        float4 hv0 = *reinterpret_cast<const float4*>(h0 + i);
        float4 hv1 = *reinterpret_cast<const float4*>(h1 + i);
        acc0 = fmaf(hv0.x, w0, fmaf(hv0.y, w1, fmaf(hv0.z, w2, fmaf(hv0.w, w3, acc0))));
        acc1 = fmaf(hv1.x, w0, fmaf(hv1.y, w1, fmaf(hv1.z, w2, fmaf(hv1.w, w3, acc1))));
    }

    ushort2 bt;
    bt.x = f2bf(acc0);
    bt.y = f2bf(acc1);
    *reinterpret_cast<ushort2*>(WhbT + (size_t)lane * 8192 + row0) = bt;

    const float a1 = a[lane] * LOG2E, a2 = a[lane + 64] * LOG2E;
    float t10 = acc0 * a1, t20 = acc0 * a2;
    float t11 = acc1 * a1, t21 = acc1 * a2;
#pragma unroll
    for (int off = 32; off; off >>= 1) {
        t10 += __shfl_xor(t10, off);
        t20 += __shfl_xor(t20, off);
        t11 += __shfl_xor(t11, off);
        t21 += __shfl_xor(t21, off);
    }
    if (lane == 0) {
        Wh1L[row0] = t10; Wh1L[row0 + 1] = t11;
        W2L[row0]  = t20; W2L[row0 + 1]  = t21;
    }
}

// ---------------- Kernel 2: fused pack + mask + softmax + PV ----------------
// grid 512 x 512 (8 waves). Block: 16 rows x 8192 cols. 2 blocks/CU.
__global__ __launch_bounds__(512) void attn_kernel(
        const int* __restrict__ adj,
        const unsigned short* __restrict__ WhbT,
        const float* __restrict__ Wh1L, const float* __restrict__ W2L,
        float* __restrict__ out) {
    __shared__ unsigned int bm_lds[16][260];   // 16.6KB
    __shared__ float sm_acc[8][64][17];        // 34.8KB, padded
    __shared__ float sm_l[8][16];              // 0.5KB

    const int tid  = threadIdx.x;
    const int w    = tid >> 6;
    const int lane = tid & 63;
    const int fr   = lane & 15;      // MFMA row (A) / col (B,D)
    const int cg   = lane >> 4;      // k-group
    const int i0   = blockIdx.x * 16;

    // ---- phase 1: stream 2 adj rows/wave -> bitmask in LDS (nt loads) ----
    {
        const int rA = w * 2, rB = w * 2 + 1;
        const int* apA = adj + (size_t)(i0 + rA) * 8192 + lane * 4;
        const int* apB = adj + (size_t)(i0 + rB) * 8192 + lane * 4;
        for (int it = 0; it < 32; it += 2) {
            int4v v0 = __builtin_nontemporal_load(reinterpret_cast<const int4v*>(apA + it * 256));
            int4v v1 = __builtin_nontemporal_load(reinterpret_cast<const int4v*>(apA + it * 256 + 256));
            int4v v2 = __builtin_nontemporal_load(reinterpret_cast<const int4v*>(apB + it * 256));
            int4v v3 = __builtin_nontemporal_load(reinterpret_cast<const int4v*>(apB + it * 256 + 256));
#pragma unroll
            for (int k = 0; k < 4; ++k) {
                const int4v v  = k == 0 ? v0 : k == 1 ? v1 : k == 2 ? v2 : v3;
                const int  rr = (k < 2) ? rA : rB;
                const int  ii = it + (k & 1);
                unsigned int n = (unsigned int)(v.x > 0)
                               | ((unsigned int)(v.y > 0) << 1)
                               | ((unsigned int)(v.z > 0) << 2)
                               | ((unsigned int)(v.w > 0) << 3);
                n |= ((unsigned int)__shfl_xor((int)n, 1)) << 4;
                n |= ((unsigned int)__shfl_xor((int)n, 2)) << 8;
                n |= ((unsigned int)__shfl_xor((int)n, 4)) << 16;
                if ((lane & 7) == 0) bm_lds[rr][ii * 8 + (lane >> 3)] = n;
            }
        }
    }
    __syncthreads();

    // ---- phase 2: masked softmax numerators + PV (L2-resident WhbT) ----
    const float wh1 = Wh1L[i0 + fr];

    f32x4 acc[4];
#pragma unroll
    for (int f = 0; f < 4; ++f) acc[f] = (f32x4){0.f, 0.f, 0.f, 0.f};
    f32x4 accl = (f32x4){0.f, 0.f, 0.f, 0.f};

    short8v ones;
#pragma unroll
    for (int b = 0; b < 8; ++b) ones[b] = (short)0x3F80;   // bf16 1.0

    const float*          w2p = W2L + w * 32 + cg * 8;
    const unsigned short* bfp = WhbT + (size_t)fr * 8192 + w * 32 + cg * 8;
    const int sh = cg * 8;

    for (int it = 0; it < 32; ++it) {
        const int cbase = it * 256;
        float4 W0 = *reinterpret_cast<const float4*>(w2p + cbase);
        float4 W1 = *reinterpret_cast<const float4*>(w2p + cbase + 4);
        short8v bf[4];
#pragma unroll
        for (int f = 0; f < 4; ++f)
            bf[f] = *reinterpret_cast<const short8v*>(bfp + (size_t)f * 16 * 8192 + cbase);

        const unsigned int wd = bm_lds[fr][it * 8 + w];

        float p[8]; float t;
        t = wh1 + W0.x; t = fmaxf(t, 0.2f * t); p[0] = ((wd >> (sh + 0)) & 1u) ? __builtin_exp2f(t) : 0.f;
        t = wh1 + W0.y; t = fmaxf(t, 0.2f * t); p[1] = ((wd >> (sh + 1)) & 1u) ? __builtin_exp2f(t) : 0.f;
        t = wh1 + W0.z; t = fmaxf(t, 0.2f * t); p[2] = ((wd >> (sh + 2)) & 1u) ? __builtin_exp2f(t) : 0.f;
        t = wh1 + W0.w; t = fmaxf(t, 0.2f * t); p[3] = ((wd >> (sh + 3)) & 1u) ? __builtin_exp2f(t) : 0.f;
        t = wh1 + W1.x; t = fmaxf(t, 0.2f * t); p[4] = ((wd >> (sh + 4)) & 1u) ? __builtin_exp2f(t) : 0.f;
        t = wh1 + W1.y; t = fmaxf(t, 0.2f * t); p[5] = ((wd >> (sh + 5)) & 1u) ? __builtin_exp2f(t) : 0.f;
        t = wh1 + W1.z; t = fmaxf(t, 0.2f * t); p[6] = ((wd >> (sh + 6)) & 1u) ? __builtin_exp2f(t) : 0.f;
        t = wh1 + W1.w; t = fmaxf(t, 0.2f * t); p[7] = ((wd >> (sh + 7)) & 1u) ? __builtin_exp2f(t) : 0.f;

        union { short8v s8; __hip_bfloat162 h2[4]; } u;
        u.h2[0] = __float22bfloat162_rn(float2{p[0], p[1]});
        u.h2[1] = __float22bfloat162_rn(float2{p[2], p[3]});
        u.h2[2] = __float22bfloat162_rn(float2{p[4], p[5]});
        u.h2[3] = __float22bfloat162_rn(float2{p[6], p[7]});

#pragma unroll
        for (int f = 0; f < 4; ++f)
            acc[f] = __builtin_amdgcn_mfma_f32_16x16x32_bf16(u.s8, bf[f], acc[f], 0, 0, 0);
        accl = __builtin_amdgcn_mfma_f32_16x16x32_bf16(u.s8, ones, accl, 0, 0, 0);
    }

    // ---- epilogue: cross-wave sums, normalize, ELU ----
    __syncthreads();
#pragma unroll
    for (int f = 0; f < 4; ++f)
#pragma unroll
        for (int reg = 0; reg < 4; ++reg)
            sm_acc[w][lane][f * 4 + reg] = acc[f][reg];
    if (fr == 0) {
#pragma unroll
        for (int reg = 0; reg < 4; ++reg) sm_l[w][4 * cg + reg] = accl[reg];
    }
    __syncthreads();

#pragma unroll
    for (int ss = 0; ss < 2; ++ss) {
        const int s = 2 * w + ss;
        const int f = s >> 2, reg = s & 3;
        float sum = 0.f;
#pragma unroll
        for (int ww = 0; ww < 8; ++ww) sum += sm_acc[ww][lane][s];
        const int R = 4 * cg + reg;
        float lrow = 0.f;
#pragma unroll
        for (int ww = 0; ww < 8; ++ww) lrow += sm_l[ww][R];
        float y = sum / lrow;
        y = y > 0.f ? y : expm1f(y);          // ELU, alpha=1
        out[(size_t)(i0 + R) * 64 + 16 * f + fr] = y;
    }
}

extern "C" void kernel_launch(void* const* d_in, const int* in_sizes, int n_in,
                              void* d_out, int out_size, void* d_ws, size_t ws_size,
                              hipStream_t stream) {
    const float* h   = (const float*)d_in[0];
    const int*   adj = (const int*)d_in[1];
    const float* W   = (const float*)d_in[2];
    const float* a   = (const float*)d_in[3];

    unsigned short* WhbT = (unsigned short*)d_ws;                    // 1 MB
    float*          Wh1L = (float*)((char*)d_ws + (1 << 20));        // 32 KB
    float*          W2L  = Wh1L + 8192;                              // 32 KB

    wh_kernel<<<1024, 256, 0, stream>>>(h, W, a, WhbT, Wh1L, W2L);
    attn_kernel<<<512, 512, 0, stream>>>(adj, WhbT, Wh1L, W2L, (float*)d_out);
}

// Round 17
// 168.410 us; speedup vs baseline: 1.0415x; 1.0272x over previous
//
#include <hip/hip_runtime.h>
#include <hip/hip_bf16.h>

// GraphAttentionLayer fused kernels for MI355X (gfx950).
// N=8192, IN=512, OUT=64.
// r15 lesson: attn time ~ V(WhbT) re-scan traffic = N^2*128/BR bits at an
// effective ~3TB/s; nt loads (L2 thrash theory) = null. r16/r17: BR=128 rows
// per block x 4 col-splits (2048 cols) => V-traffic 512MB -> 64MB. Waves split
// ROWS: each wave packs its own 16 rows' adj bits into its own LDS slice and
// consumes them -- NO __syncthreads in attn, no cross-wave reduce. Partial
// numerators/denominators per col-block -> ws; combine kernel sums + ELU.
// (Resubmission of r16 -- container died before measurement.)

#define LOG2E 1.4426950408889634f

typedef __attribute__((ext_vector_type(8))) short  short8v;
typedef __attribute__((ext_vector_type(4))) float  f32x4;
typedef __attribute__((ext_vector_type(4))) int    int4v;

__device__ __forceinline__ unsigned short f2bf(float f) {
    union { float f; unsigned int u; } x; x.f = f;
    unsigned int r = x.u + 0x7FFFu + ((x.u >> 16) & 1u);   // RNE
    return (unsigned short)(r >> 16);
}

// ---------------- Kernel 1: wh (1024 blocks, 2 rows/wave) ----------
__global__ __launch_bounds__(256) void wh_kernel(
        const float* __restrict__ h, const float* __restrict__ W,
        const float* __restrict__ a,
        unsigned short* __restrict__ WhbT,
        float* __restrict__ Wh1L, float* __restrict__ W2L) {
    const int wave = threadIdx.x >> 6;
    const int lane = threadIdx.x & 63;
    const int row0 = (blockIdx.x * 4 + wave) * 2;

    float acc0 = 0.f, acc1 = 0.f;
    const float* h0 = h + (size_t)row0 * 512;
    const float* h1 = h0 + 512;
    for (int i = 0; i < 512; i += 4) {
        float w0 = W[(i + 0) * 64 + lane];
        float w1 = W[(i + 1) * 64 + lane];
        float w2 = W[(i + 2) * 64 + lane];
        float w3 = W[(i + 3) * 64 + lane];
        float4 hv0 = *reinterpret_cast<const float4*>(h0 + i);
        float4 hv1 = *reinterpret_cast<const float4*>(h1 + i);
        acc0 = fmaf(hv0.x, w0, fmaf(hv0.y, w1, fmaf(hv0.z, w2, fmaf(hv0.w, w3, acc0))));
        acc1 = fmaf(hv1.x, w0, fmaf(hv1.y, w1, fmaf(hv1.z, w2, fmaf(hv1.w, w3, acc1))));
    }

    ushort2 bt;
    bt.x = f2bf(acc0);
    bt.y = f2bf(acc1);
    *reinterpret_cast<ushort2*>(WhbT + (size_t)lane * 8192 + row0) = bt;

    const float a1 = a[lane] * LOG2E, a2 = a[lane + 64] * LOG2E;
    float t10 = acc0 * a1, t20 = acc0 * a2;
    float t11 = acc1 * a1, t21 = acc1 * a2;
#pragma unroll
    for (int off = 32; off; off >>= 1) {
        t10 += __shfl_xor(t10, off);
        t20 += __shfl_xor(t20, off);
        t11 += __shfl_xor(t11, off);
        t21 += __shfl_xor(t21, off);
    }
    if (lane == 0) {
        Wh1L[row0] = t10; Wh1L[row0 + 1] = t11;
        W2L[row0]  = t20; W2L[row0 + 1]  = t21;
    }
}

// ---------------- Kernel 2: per-wave pack + masked softmax + PV -------------
// grid 256 x 512 (8 waves). Block (rb,cb): rows [rb*128,+128), cols
// [cb*2048,+2048). Wave w owns rows rb*128 + w*16 + (0..15). No barriers.
__global__ __launch_bounds__(512) void attn_kernel(
        const int* __restrict__ adj,
        const unsigned short* __restrict__ WhbT,
        const float* __restrict__ Wh1L, const float* __restrict__ W2L,
        float* __restrict__ nump, float* __restrict__ lp) {
    __shared__ unsigned int bm_lds[8][16][65];   // 33.3KB, wave-private slices

    const int tid  = threadIdx.x;
    const int w    = tid >> 6;
    const int lane = tid & 63;
    const int fr   = lane & 15;
    const int cg   = lane >> 4;
    const int rb   = blockIdx.x >> 2;
    const int cb   = blockIdx.x & 3;
    const int r0   = rb * 128 + w * 16;     // wave's first row
    const int c0   = cb * 2048;             // block's first col

    // ---- phase 1 (per wave): pack 16 rows x 2048 cols -> own LDS slice ----
    for (int rr = 0; rr < 16; ++rr) {
        const int* ap = adj + (size_t)(r0 + rr) * 8192 + c0 + lane * 4;
        int4v v[8];
#pragma unroll
        for (int it = 0; it < 8; ++it)
            v[it] = __builtin_nontemporal_load(reinterpret_cast<const int4v*>(ap + it * 256));
#pragma unroll
        for (int it = 0; it < 8; ++it) {
            unsigned int n = (unsigned int)(v[it].x > 0)
                           | ((unsigned int)(v[it].y > 0) << 1)
                           | ((unsigned int)(v[it].z > 0) << 2)
                           | ((unsigned int)(v[it].w > 0) << 3);
            n |= ((unsigned int)__shfl_xor((int)n, 1)) << 4;
            n |= ((unsigned int)__shfl_xor((int)n, 2)) << 8;
            n |= ((unsigned int)__shfl_xor((int)n, 4)) << 16;
            if ((lane & 7) == 0) bm_lds[w][rr][it * 8 + (lane >> 3)] = n;
        }
    }
    // no __syncthreads: wave reads only its own slice

    // ---- phase 2 (per wave): 64 col-tiles of 32, masked p -> 5 MFMA --------
    const float wh1 = Wh1L[r0 + fr];

    f32x4 acc[4];
#pragma unroll
    for (int f = 0; f < 4; ++f) acc[f] = (f32x4){0.f, 0.f, 0.f, 0.f};
    f32x4 accl = (f32x4){0.f, 0.f, 0.f, 0.f};

    short8v ones;
#pragma unroll
    for (int b = 0; b < 8; ++b) ones[b] = (short)0x3F80;   // bf16 1.0

    const float*          w2p = W2L + c0 + cg * 8;
    const unsigned short* bfp = WhbT + (size_t)fr * 8192 + c0 + cg * 8;
    const int sh = cg * 8;

    for (int it = 0; it < 64; ++it) {
        const int cbase = it * 32;
        float4 W0 = *reinterpret_cast<const float4*>(w2p + cbase);
        float4 W1 = *reinterpret_cast<const float4*>(w2p + cbase + 4);
        short8v bf[4];
#pragma unroll
        for (int f = 0; f < 4; ++f)
            bf[f] = *reinterpret_cast<const short8v*>(bfp + (size_t)f * 16 * 8192 + cbase);

        const unsigned int wd = bm_lds[w][fr][it];

        float p[8]; float t;
        t = wh1 + W0.x; t = fmaxf(t, 0.2f * t); p[0] = ((wd >> (sh + 0)) & 1u) ? __builtin_exp2f(t) : 0.f;
        t = wh1 + W0.y; t = fmaxf(t, 0.2f * t); p[1] = ((wd >> (sh + 1)) & 1u) ? __builtin_exp2f(t) : 0.f;
        t = wh1 + W0.z; t = fmaxf(t, 0.2f * t); p[2] = ((wd >> (sh + 2)) & 1u) ? __builtin_exp2f(t) : 0.f;
        t = wh1 + W0.w; t = fmaxf(t, 0.2f * t); p[3] = ((wd >> (sh + 3)) & 1u) ? __builtin_exp2f(t) : 0.f;
        t = wh1 + W1.x; t = fmaxf(t, 0.2f * t); p[4] = ((wd >> (sh + 4)) & 1u) ? __builtin_exp2f(t) : 0.f;
        t = wh1 + W1.y; t = fmaxf(t, 0.2f * t); p[5] = ((wd >> (sh + 5)) & 1u) ? __builtin_exp2f(t) : 0.f;
        t = wh1 + W1.z; t = fmaxf(t, 0.2f * t); p[6] = ((wd >> (sh + 6)) & 1u) ? __builtin_exp2f(t) : 0.f;
        t = wh1 + W1.w; t = fmaxf(t, 0.2f * t); p[7] = ((wd >> (sh + 7)) & 1u) ? __builtin_exp2f(t) : 0.f;

        union { short8v s8; __hip_bfloat162 h2[4]; } u;
        u.h2[0] = __float22bfloat162_rn(float2{p[0], p[1]});
        u.h2[1] = __float22bfloat162_rn(float2{p[2], p[3]});
        u.h2[2] = __float22bfloat162_rn(float2{p[4], p[5]});
        u.h2[3] = __float22bfloat162_rn(float2{p[6], p[7]});

#pragma unroll
        for (int f = 0; f < 4; ++f)
            acc[f] = __builtin_amdgcn_mfma_f32_16x16x32_bf16(u.s8, bf[f], acc[f], 0, 0, 0);
        accl = __builtin_amdgcn_mfma_f32_16x16x32_bf16(u.s8, ones, accl, 0, 0, 0);
    }

    // ---- write partials: num[cb][row][feat], l[cb][row] (no reduce) --------
    float* nb = nump + (size_t)cb * 8192 * 64;
#pragma unroll
    for (int f = 0; f < 4; ++f)
#pragma unroll
        for (int reg = 0; reg < 4; ++reg)
            nb[(size_t)(r0 + 4 * cg + reg) * 64 + 16 * f + fr] = acc[f][reg];
    if (fr == 0) {
#pragma unroll
        for (int reg = 0; reg < 4; ++reg)
            lp[(size_t)cb * 8192 + r0 + 4 * cg + reg] = accl[reg];
    }
}

// ---------------- Kernel 3: combine col-blocks, normalize, ELU --------------
__global__ __launch_bounds__(256) void combine_kernel(
        const float* __restrict__ nump, const float* __restrict__ lp,
        float* __restrict__ out) {
    const int idx = blockIdx.x * 256 + threadIdx.x;
    const int row = idx >> 6;
    float s = nump[idx] + nump[idx + 8192 * 64] + nump[idx + 2 * 8192 * 64]
            + nump[idx + 3 * 8192 * 64];
    float l = lp[row] + lp[row + 8192] + lp[row + 2 * 8192] + lp[row + 3 * 8192];
    float y = s / l;
    y = y > 0.f ? y : expm1f(y);   // ELU, alpha=1
    out[idx] = y;
}

extern "C" void kernel_launch(void* const* d_in, const int* in_sizes, int n_in,
                              void* d_out, int out_size, void* d_ws, size_t ws_size,
                              hipStream_t stream) {
    const float* h   = (const float*)d_in[0];
    const int*   adj = (const int*)d_in[1];
    const float* W   = (const float*)d_in[2];
    const float* a   = (const float*)d_in[3];

    unsigned short* WhbT = (unsigned short*)d_ws;                    // 1 MB
    float*          Wh1L = (float*)((char*)d_ws + (1 << 20));        // 32 KB
    float*          W2L  = Wh1L + 8192;                              // 32 KB
    float*          nump = (float*)((char*)d_ws + (2 << 20));        // 8 MB
    float*          lp   = nump + 4 * 8192 * 64;                     // 128 KB

    wh_kernel<<<1024, 256, 0, stream>>>(h, W, a, WhbT, Wh1L, W2L);
    attn_kernel<<<256, 512, 0, stream>>>(adj, WhbT, Wh1L, W2L, nump, lp);
    combine_kernel<<<2048, 256, 0, stream>>>(nump, lp, (float*)d_out);
}

// Round 20
// 160.215 us; speedup vs baseline: 1.0947x; 1.0512x over previous
//
#include <hip/hip_runtime.h>
#include <hip/hip_bf16.h>

// GraphAttentionLayer fused kernels for MI355X (gfx950).
// N=8192, IN=512, OUT=64.
// 17-round lesson: kernels that stream the 256MB adj INSIDE a compute block
// all land 150-165us regardless of structure; r11's class separation (pure
// streaming pack kernel at 32 waves/CU -> 8MB bitmask; compute kernel reads
// bitmask) = 121us, the best. r18/r19/r20 = r11 pack_wh (unchanged) +
// wave-private attn-on-bitmask: block = 128 rows x 1024 cols, wave owns 16
// rows, zero barriers, V-traffic 64MB, partials -> ws, combine over 8 splits.
// (Second resubmission -- container died before measurement twice.)

#define LOG2E 1.4426950408889634f

typedef __attribute__((ext_vector_type(8))) short  short8v;
typedef __attribute__((ext_vector_type(8))) unsigned short ushort8v;
typedef __attribute__((ext_vector_type(4))) float  f32x4;

__device__ __forceinline__ unsigned short f2bf(float f) {
    union { float f; unsigned int u; } x; x.f = f;
    unsigned int r = x.u + 0x7FFFu + ((x.u >> 16) & 1u);   // RNE
    return (unsigned short)(r >> 16);
}

// ---------------- Kernel 1: wh (blocks 0..255) + pack (blocks 256..2303) ----
// (r11's kernel, byte-identical: proven 121us-config component.)
__global__ __launch_bounds__(256) void pack_wh_kernel(
        const float* __restrict__ h, const int* __restrict__ adj,
        const float* __restrict__ W, const float* __restrict__ a,
        unsigned int* __restrict__ bmask,
        unsigned short* __restrict__ WhbT,
        float* __restrict__ Wh1L, float* __restrict__ W2L) {
    const int wave = threadIdx.x >> 6;
    const int lane = threadIdx.x & 63;

    if (blockIdx.x >= 256) {
        // pack role: wave -> one adj row; word w covers cols [w*32,+32),
        // bit b = col w*32+b.
        const int row = (blockIdx.x - 256) * 4 + wave;
        const int4* ap4 = reinterpret_cast<const int4*>(adj + (size_t)row * 8192);
        unsigned int* bmp = bmask + (size_t)row * 256;
#pragma unroll 4
        for (int it = 0; it < 32; ++it) {
            int4 v = ap4[it * 64 + lane];          // 16B/lane, 1KB/wave
            unsigned int n = (unsigned int)(v.x > 0)
                           | ((unsigned int)(v.y > 0) << 1)
                           | ((unsigned int)(v.z > 0) << 2)
                           | ((unsigned int)(v.w > 0) << 3);
            n |= ((unsigned int)__shfl_xor((int)n, 1)) << 4;
            n |= ((unsigned int)__shfl_xor((int)n, 2)) << 8;
            n |= ((unsigned int)__shfl_xor((int)n, 4)) << 16;
            if ((lane & 7) == 0) bmp[it * 8 + (lane >> 3)] = n;
        }
        return;
    }

    // wh role (256 blocks): 8 rows/wave
    const int row0 = (blockIdx.x * 4 + wave) * 8;

    float acc[8];
#pragma unroll
    for (int rr = 0; rr < 8; ++rr) acc[rr] = 0.f;

    const float* hrow = h + (size_t)row0 * 512;
    for (int i = 0; i < 512; i += 4) {
        float w0 = W[(i + 0) * 64 + lane];
        float w1 = W[(i + 1) * 64 + lane];
        float w2 = W[(i + 2) * 64 + lane];
        float w3 = W[(i + 3) * 64 + lane];
#pragma unroll
        for (int rr = 0; rr < 8; ++rr) {
            float4 hv = *reinterpret_cast<const float4*>(hrow + (size_t)rr * 512 + i);
            acc[rr] = fmaf(hv.x, w0, fmaf(hv.y, w1, fmaf(hv.z, w2, fmaf(hv.w, w3, acc[rr]))));
        }
    }

    ushort8v bt;
#pragma unroll
    for (int rr = 0; rr < 8; ++rr) bt[rr] = f2bf(acc[rr]);
    *reinterpret_cast<ushort8v*>(WhbT + (size_t)lane * 8192 + row0) = bt;

    const float a1 = a[lane] * LOG2E, a2 = a[lane + 64] * LOG2E;
#pragma unroll
    for (int rr = 0; rr < 8; ++rr) {
        float t1 = acc[rr] * a1;
        float t2 = acc[rr] * a2;
#pragma unroll
        for (int off = 32; off; off >>= 1) {
            t1 += __shfl_xor(t1, off);
            t2 += __shfl_xor(t2, off);
        }
        if (lane == 0) { Wh1L[row0 + rr] = t1; W2L[row0 + rr] = t2; }
    }
}

// ---------------- Kernel 2: wave-private attn on bitmask --------------------
// grid 512 x 512 (8 waves), no barriers. Block (rb,cb): rows [rb*128,+128),
// cols [cb*1024,+1024). Wave w owns rows rb*128+w*16+(0..15), all 1024 cols.
__global__ __launch_bounds__(512) void attn_kernel(
        const unsigned int* __restrict__ bmask,
        const unsigned short* __restrict__ WhbT,
        const float* __restrict__ Wh1L, const float* __restrict__ W2L,
        float* __restrict__ nump, float* __restrict__ lp) {
    __shared__ unsigned int bm_lds[8][512];   // 16KB, wave-private slices

    const int tid  = threadIdx.x;
    const int w    = tid >> 6;
    const int lane = tid & 63;
    const int fr   = lane & 15;
    const int cg   = lane >> 4;
    const int rb   = blockIdx.x >> 3;
    const int cb   = blockIdx.x & 7;
    const int r0   = rb * 128 + w * 16;     // wave's first row
    const int c0   = cb * 1024;             // block's first col
    const int c0w  = cb * 32;               // first bitmask word

    // ---- wave-private bitmask slice load: 16 rows x 32 words, 2 int4/lane --
    {
        const int rr = lane >> 2;            // 0..15
        const int wo = (lane & 3) * 8;       // word offset within row: 0,8,16,24
        const unsigned int* gp = bmask + (size_t)(r0 + rr) * 256 + c0w + wo;
        *reinterpret_cast<int4*>(&bm_lds[w][rr * 32 + wo])     = *reinterpret_cast<const int4*>(gp);
        *reinterpret_cast<int4*>(&bm_lds[w][rr * 32 + wo + 4]) = *reinterpret_cast<const int4*>(gp + 4);
    }
    // no __syncthreads: wave reads only its own slice (LDS ops in-order per wave)

    const float wh1 = Wh1L[r0 + fr];

    f32x4 acc[4];
#pragma unroll
    for (int f = 0; f < 4; ++f) acc[f] = (f32x4){0.f, 0.f, 0.f, 0.f};
    f32x4 accl = (f32x4){0.f, 0.f, 0.f, 0.f};

    short8v ones;
#pragma unroll
    for (int b = 0; b < 8; ++b) ones[b] = (short)0x3F80;   // bf16 1.0

    const float*          w2p = W2L + c0 + cg * 8;
    const unsigned short* bfp = WhbT + (size_t)fr * 8192 + c0 + cg * 8;
    const int sh = cg * 8;

    for (int it = 0; it < 32; ++it) {
        const int cbase = it * 32;
        float4 W0 = *reinterpret_cast<const float4*>(w2p + cbase);
        float4 W1 = *reinterpret_cast<const float4*>(w2p + cbase + 4);
        short8v bf[4];
#pragma unroll
        for (int f = 0; f < 4; ++f)
            bf[f] = *reinterpret_cast<const short8v*>(bfp + (size_t)f * 16 * 8192 + cbase);

        const unsigned int wd = bm_lds[w][fr * 32 + it];

        float p[8]; float t;
        t = wh1 + W0.x; t = fmaxf(t, 0.2f * t); p[0] = ((wd >> (sh + 0)) & 1u) ? __builtin_exp2f(t) : 0.f;
        t = wh1 + W0.y; t = fmaxf(t, 0.2f * t); p[1] = ((wd >> (sh + 1)) & 1u) ? __builtin_exp2f(t) : 0.f;
        t = wh1 + W0.z; t = fmaxf(t, 0.2f * t); p[2] = ((wd >> (sh + 2)) & 1u) ? __builtin_exp2f(t) : 0.f;
        t = wh1 + W0.w; t = fmaxf(t, 0.2f * t); p[3] = ((wd >> (sh + 3)) & 1u) ? __builtin_exp2f(t) : 0.f;
        t = wh1 + W1.x; t = fmaxf(t, 0.2f * t); p[4] = ((wd >> (sh + 4)) & 1u) ? __builtin_exp2f(t) : 0.f;
        t = wh1 + W1.y; t = fmaxf(t, 0.2f * t); p[5] = ((wd >> (sh + 5)) & 1u) ? __builtin_exp2f(t) : 0.f;
        t = wh1 + W1.z; t = fmaxf(t, 0.2f * t); p[6] = ((wd >> (sh + 6)) & 1u) ? __builtin_exp2f(t) : 0.f;
        t = wh1 + W1.w; t = fmaxf(t, 0.2f * t); p[7] = ((wd >> (sh + 7)) & 1u) ? __builtin_exp2f(t) : 0.f;

        union { short8v s8; __hip_bfloat162 h2[4]; } u;
        u.h2[0] = __float22bfloat162_rn(float2{p[0], p[1]});
        u.h2[1] = __float22bfloat162_rn(float2{p[2], p[3]});
        u.h2[2] = __float22bfloat162_rn(float2{p[4], p[5]});
        u.h2[3] = __float22bfloat162_rn(float2{p[6], p[7]});

#pragma unroll
        for (int f = 0; f < 4; ++f)
            acc[f] = __builtin_amdgcn_mfma_f32_16x16x32_bf16(u.s8, bf[f], acc[f], 0, 0, 0);
        accl = __builtin_amdgcn_mfma_f32_16x16x32_bf16(u.s8, ones, accl, 0, 0, 0);
    }

    // ---- write partials: num[cb][row][feat], l[cb][row] (no reduce) --------
    float* nb = nump + (size_t)cb * 8192 * 64;
#pragma unroll
    for (int f = 0; f < 4; ++f)
#pragma unroll
        for (int reg = 0; reg < 4; ++reg)
            nb[(size_t)(r0 + 4 * cg + reg) * 64 + 16 * f + fr] = acc[f][reg];
    if (fr == 0) {
#pragma unroll
        for (int reg = 0; reg < 4; ++reg)
            lp[(size_t)cb * 8192 + r0 + 4 * cg + reg] = accl[reg];
    }
}

// ---------------- Kernel 3: combine col-splits, normalize, ELU --------------
__global__ __launch_bounds__(256) void combine_kernel(
        const float* __restrict__ nump, const float* __restrict__ lp,
        float* __restrict__ out) {
    const int idx = blockIdx.x * 256 + threadIdx.x;
    const int row = idx >> 6;
    float s = 0.f, l = 0.f;
#pragma unroll
    for (int cb = 0; cb < 8; ++cb) {
        s += nump[(size_t)cb * 8192 * 64 + idx];
        l += lp[(size_t)cb * 8192 + row];
    }
    float y = s / l;
    y = y > 0.f ? y : expm1f(y);   // ELU, alpha=1
    out[idx] = y;
}

extern "C" void kernel_launch(void* const* d_in, const int* in_sizes, int n_in,
                              void* d_out, int out_size, void* d_ws, size_t ws_size,
                              hipStream_t stream) {
    const float* h   = (const float*)d_in[0];
    const int*   adj = (const int*)d_in[1];
    const float* W   = (const float*)d_in[2];
    const float* a   = (const float*)d_in[3];

    unsigned short* WhbT  = (unsigned short*)d_ws;                    // 1 MB
    float*          Wh1L  = (float*)((char*)d_ws + (1 << 20));        // 32 KB
    float*          W2L   = Wh1L + 8192;                              // 32 KB
    unsigned int*   bmask = (unsigned int*)((char*)d_ws + (2 << 20)); // 8 MB
    float*          nump  = (float*)((char*)d_ws + (12 << 20));       // 16 MB
    float*          lp    = nump + (size_t)8 * 8192 * 64;             // 256 KB

    pack_wh_kernel<<<2304, 256, 0, stream>>>(h, adj, W, a, bmask, WhbT, Wh1L, W2L);
    attn_kernel<<<512, 512, 0, stream>>>(bmask, WhbT, Wh1L, W2L, nump, lp);
    combine_kernel<<<2048, 256, 0, stream>>>(nump, lp, (float*)d_out);
}

// Round 21
// 140.626 us; speedup vs baseline: 1.2472x; 1.1393x over previous
//
#include <hip/hip_runtime.h>
#include <hip/hip_bf16.h>

// GraphAttentionLayer fused kernels for MI355X (gfx950).
// N=8192, IN=512, OUT=64.
// 20-round lesson: attn time tracks per-wave WhbT re-scan bytes (~4.3TB/s
// effective for scattered 16B/lane loads). r21: V-STATIONARY attn — wave
// holds its V-slice (128 j x 64 f = 16 short8v = 64 VGPR) in registers,
// streams only LDS-resident bitmask/score-vector data. V-reads 256MB -> 8MB.
//  K1 pack_wh: byte-identical r11 (proven): blocks 0..255 wh, 256..2303 pack
//     adj -> bitmask via int4 + shfl merge at 32 waves/CU.
//  K2 attn_vstat: grid 64qb x 8cb; block 128 q x 1024 j, 8 waves split j.
//     Preload bitmask-slice/Wh1L/W2L to LDS; per q-tile: LDS + VALU + 20 MFMA,
//     cross-wave LDS reduce, partial (over 1024 j) -> nump[cb].
//  K3 combine: out = ELU( sum_cb num / sum_cb l ).

#define LOG2E 1.4426950408889634f

typedef __attribute__((ext_vector_type(8))) short  short8v;
typedef __attribute__((ext_vector_type(8))) unsigned short ushort8v;
typedef __attribute__((ext_vector_type(4))) float  f32x4;

__device__ __forceinline__ unsigned short f2bf(float f) {
    union { float f; unsigned int u; } x; x.f = f;
    unsigned int r = x.u + 0x7FFFu + ((x.u >> 16) & 1u);   // RNE
    return (unsigned short)(r >> 16);
}

// ---------------- Kernel 1: wh (blocks 0..255) + pack (blocks 256..2303) ----
__global__ __launch_bounds__(256) void pack_wh_kernel(
        const float* __restrict__ h, const int* __restrict__ adj,
        const float* __restrict__ W, const float* __restrict__ a,
        unsigned int* __restrict__ bmask,
        unsigned short* __restrict__ WhbT,
        float* __restrict__ Wh1L, float* __restrict__ W2L) {
    const int wave = threadIdx.x >> 6;
    const int lane = threadIdx.x & 63;

    if (blockIdx.x >= 256) {
        const int row = (blockIdx.x - 256) * 4 + wave;
        const int4* ap4 = reinterpret_cast<const int4*>(adj + (size_t)row * 8192);
        unsigned int* bmp = bmask + (size_t)row * 256;
#pragma unroll 4
        for (int it = 0; it < 32; ++it) {
            int4 v = ap4[it * 64 + lane];          // 16B/lane, 1KB/wave
            unsigned int n = (unsigned int)(v.x > 0)
                           | ((unsigned int)(v.y > 0) << 1)
                           | ((unsigned int)(v.z > 0) << 2)
                           | ((unsigned int)(v.w > 0) << 3);
            n |= ((unsigned int)__shfl_xor((int)n, 1)) << 4;
            n |= ((unsigned int)__shfl_xor((int)n, 2)) << 8;
            n |= ((unsigned int)__shfl_xor((int)n, 4)) << 16;
            if ((lane & 7) == 0) bmp[it * 8 + (lane >> 3)] = n;
        }
        return;
    }

    const int row0 = (blockIdx.x * 4 + wave) * 8;

    float acc[8];
#pragma unroll
    for (int rr = 0; rr < 8; ++rr) acc[rr] = 0.f;

    const float* hrow = h + (size_t)row0 * 512;
    for (int i = 0; i < 512; i += 4) {
        float w0 = W[(i + 0) * 64 + lane];
        float w1 = W[(i + 1) * 64 + lane];
        float w2 = W[(i + 2) * 64 + lane];
        float w3 = W[(i + 3) * 64 + lane];
#pragma unroll
        for (int rr = 0; rr < 8; ++rr) {
            float4 hv = *reinterpret_cast<const float4*>(hrow + (size_t)rr * 512 + i);
            acc[rr] = fmaf(hv.x, w0, fmaf(hv.y, w1, fmaf(hv.z, w2, fmaf(hv.w, w3, acc[rr]))));
        }
    }

    ushort8v bt;
#pragma unroll
    for (int rr = 0; rr < 8; ++rr) bt[rr] = f2bf(acc[rr]);
    *reinterpret_cast<ushort8v*>(WhbT + (size_t)lane * 8192 + row0) = bt;

    const float a1 = a[lane] * LOG2E, a2 = a[lane + 64] * LOG2E;
#pragma unroll
    for (int rr = 0; rr < 8; ++rr) {
        float t1 = acc[rr] * a1;
        float t2 = acc[rr] * a2;
#pragma unroll
        for (int off = 32; off; off >>= 1) {
            t1 += __shfl_xor(t1, off);
            t2 += __shfl_xor(t2, off);
        }
        if (lane == 0) { Wh1L[row0 + rr] = t1; W2L[row0 + rr] = t2; }
    }
}

// ---------------- Kernel 2: V-stationary attention -------------------------
// grid 512 x 512 (8 waves). Block (qb,cb): q [qb*128,+128), j [cb*1024,+1024).
// Wave w owns j-sub [cb*1024 + w*128, +128) held in registers.
__global__ __launch_bounds__(512) void attn_vstat(
        const unsigned int* __restrict__ bmask,
        const unsigned short* __restrict__ WhbT,
        const float* __restrict__ Wh1L, const float* __restrict__ W2L,
        float* __restrict__ nump, float* __restrict__ lp) {
    __shared__ unsigned int bm_lds[128][33];   // 16.9KB (pad: conflict-free)
    __shared__ float wh1_lds[128];             // 0.5KB
    __shared__ float w2_lds[1024];             // 4KB
    __shared__ float sm_acc[8][64][17];        // 34.8KB
    __shared__ float sm_l[8][16];              // 0.5KB

    const int tid  = threadIdx.x;
    const int w    = tid >> 6;
    const int lane = tid & 63;
    const int fr   = lane & 15;      // A row (q) / B,D col (feat)
    const int cg   = lane >> 4;      // k-group
    const int qb   = blockIdx.x >> 3;
    const int cb   = blockIdx.x & 7;
    const int q0   = qb * 128;
    const int c0   = cb * 1024;
    const int jw   = c0 + w * 128;   // wave's first j

    // ---- V-slice into registers: 16 short8v = 64 VGPR (L2-resident WhbT) ---
    short8v bfv[4][4];
#pragma unroll
    for (int s = 0; s < 4; ++s)
#pragma unroll
        for (int f = 0; f < 4; ++f)
            bfv[s][f] = *reinterpret_cast<const short8v*>(
                WhbT + (size_t)(f * 16 + fr) * 8192 + jw + s * 32 + cg * 8);

    // ---- cooperative LDS preload: bitmask slice, Wh1L, W2L ----
    for (int c = tid; c < 1024; c += 512) {
        const int row = c >> 3, wg = (c & 7) * 4;
        *reinterpret_cast<int4*>(&bm_lds[row][wg]) =
            *reinterpret_cast<const int4*>(bmask + (size_t)(q0 + row) * 256 + cb * 32 + wg);
    }
    if (tid < 128) wh1_lds[tid] = Wh1L[q0 + tid];
    w2_lds[tid]       = W2L[c0 + tid];
    w2_lds[tid + 512] = W2L[c0 + tid + 512];
    __syncthreads();

    short8v ones;
#pragma unroll
    for (int b = 0; b < 8; ++b) ones[b] = (short)0x3F80;   // bf16 1.0

    float* nb = nump + (size_t)cb * 8192 * 64;

    for (int t4 = 0; t4 < 8; ++t4) {          // 8 q-tiles of 16 rows
        const int qt = t4 * 16;
        const float wh1 = wh1_lds[qt + fr];

        f32x4 acc[4];
#pragma unroll
        for (int f = 0; f < 4; ++f) acc[f] = (f32x4){0.f, 0.f, 0.f, 0.f};
        f32x4 accl = (f32x4){0.f, 0.f, 0.f, 0.f};

#pragma unroll
        for (int s = 0; s < 4; ++s) {         // 4 k-steps of 32 j
            const unsigned int wd = bm_lds[qt + fr][w * 4 + s];
            const int sh = cg * 8;
            const float4 W0 = *reinterpret_cast<const float4*>(&w2_lds[w * 128 + s * 32 + cg * 8]);
            const float4 W1 = *reinterpret_cast<const float4*>(&w2_lds[w * 128 + s * 32 + cg * 8 + 4]);

            float p[8]; float t;
            t = wh1 + W0.x; t = fmaxf(t, 0.2f * t); p[0] = ((wd >> (sh + 0)) & 1u) ? __builtin_exp2f(t) : 0.f;
            t = wh1 + W0.y; t = fmaxf(t, 0.2f * t); p[1] = ((wd >> (sh + 1)) & 1u) ? __builtin_exp2f(t) : 0.f;
            t = wh1 + W0.z; t = fmaxf(t, 0.2f * t); p[2] = ((wd >> (sh + 2)) & 1u) ? __builtin_exp2f(t) : 0.f;
            t = wh1 + W0.w; t = fmaxf(t, 0.2f * t); p[3] = ((wd >> (sh + 3)) & 1u) ? __builtin_exp2f(t) : 0.f;
            t = wh1 + W1.x; t = fmaxf(t, 0.2f * t); p[4] = ((wd >> (sh + 4)) & 1u) ? __builtin_exp2f(t) : 0.f;
            t = wh1 + W1.y; t = fmaxf(t, 0.2f * t); p[5] = ((wd >> (sh + 5)) & 1u) ? __builtin_exp2f(t) : 0.f;
            t = wh1 + W1.z; t = fmaxf(t, 0.2f * t); p[6] = ((wd >> (sh + 6)) & 1u) ? __builtin_exp2f(t) : 0.f;
            t = wh1 + W1.w; t = fmaxf(t, 0.2f * t); p[7] = ((wd >> (sh + 7)) & 1u) ? __builtin_exp2f(t) : 0.f;

            union { short8v s8; __hip_bfloat162 h2[4]; } u;
            u.h2[0] = __float22bfloat162_rn(float2{p[0], p[1]});
            u.h2[1] = __float22bfloat162_rn(float2{p[2], p[3]});
            u.h2[2] = __float22bfloat162_rn(float2{p[4], p[5]});
            u.h2[3] = __float22bfloat162_rn(float2{p[6], p[7]});

#pragma unroll
            for (int f = 0; f < 4; ++f)
                acc[f] = __builtin_amdgcn_mfma_f32_16x16x32_bf16(u.s8, bfv[s][f], acc[f], 0, 0, 0);
            accl = __builtin_amdgcn_mfma_f32_16x16x32_bf16(u.s8, ones, accl, 0, 0, 0);
        }

        // ---- cross-wave reduce (waves hold different j-subranges) ----
#pragma unroll
        for (int f = 0; f < 4; ++f)
#pragma unroll
            for (int reg = 0; reg < 4; ++reg)
                sm_acc[w][lane][f * 4 + reg] = acc[f][reg];
        if (fr == 0) {
#pragma unroll
            for (int reg = 0; reg < 4; ++reg) sm_l[w][4 * cg + reg] = accl[reg];
        }
        __syncthreads();

#pragma unroll
        for (int ss = 0; ss < 2; ++ss) {
            const int s = 2 * w + ss;
            const int f = s >> 2, reg = s & 3;
            float sum = 0.f;
#pragma unroll
            for (int ww = 0; ww < 8; ++ww) sum += sm_acc[ww][lane][s];
            const int R = 4 * cg + reg;
            nb[(size_t)(q0 + qt + R) * 64 + 16 * f + fr] = sum;
            if (f == 0 && fr == 0) {
                float lrow = 0.f;
#pragma unroll
                for (int ww = 0; ww < 8; ++ww) lrow += sm_l[ww][R];
                lp[(size_t)cb * 8192 + q0 + qt + R] = lrow;
            }
        }
        __syncthreads();   // sm_acc reused next q-tile
    }
}

// ---------------- Kernel 3: combine col-splits, normalize, ELU --------------
__global__ __launch_bounds__(256) void combine_kernel(
        const float* __restrict__ nump, const float* __restrict__ lp,
        float* __restrict__ out) {
    const int idx = blockIdx.x * 256 + threadIdx.x;
    const int row = idx >> 6;
    float s = 0.f, l = 0.f;
#pragma unroll
    for (int cb = 0; cb < 8; ++cb) {
        s += nump[(size_t)cb * 8192 * 64 + idx];
        l += lp[(size_t)cb * 8192 + row];
    }
    float y = s / l;
    y = y > 0.f ? y : expm1f(y);   // ELU, alpha=1
    out[idx] = y;
}

extern "C" void kernel_launch(void* const* d_in, const int* in_sizes, int n_in,
                              void* d_out, int out_size, void* d_ws, size_t ws_size,
                              hipStream_t stream) {
    const float* h   = (const float*)d_in[0];
    const int*   adj = (const int*)d_in[1];
    const float* W   = (const float*)d_in[2];
    const float* a   = (const float*)d_in[3];

    unsigned short* WhbT  = (unsigned short*)d_ws;                    // 1 MB
    float*          Wh1L  = (float*)((char*)d_ws + (1 << 20));        // 32 KB
    float*          W2L   = Wh1L + 8192;                              // 32 KB
    unsigned int*   bmask = (unsigned int*)((char*)d_ws + (2 << 20)); // 8 MB
    float*          nump  = (float*)((char*)d_ws + (12 << 20));       // 16 MB
    float*          lp    = nump + (size_t)8 * 8192 * 64;             // 256 KB

    pack_wh_kernel<<<2304, 256, 0, stream>>>(h, adj, W, a, bmask, WhbT, Wh1L, W2L);
    attn_vstat<<<512, 512, 0, stream>>>(bmask, WhbT, Wh1L, W2L, nump, lp);
    combine_kernel<<<2048, 256, 0, stream>>>(nump, lp, (float*)d_out);
}